// Round 14
// baseline (425.698 us; speedup 1.0000x reference)
//
#include <hip/hip_runtime.h>
#include <hip/hip_bf16.h>

#define NN 50000
#define EE 800000
#define IN_DIM 64
#define DS_DIM 32
#define HOUT_DIM 64

#define K4_WAVES 10000
#define K4_EPW   80
#define K4_C     5
#define K4_NWG   (K4_WAVES / 4)   // 2500

#define HIST_BLOCKS 3125   // EE/256
#define ENC_BLOCKS  6250   // NN*32/256

#define SCAN_NB 196        // ceil(NN/256)

#define XPS 72             // bf16 LDS row stride (144B = 9*16B)
#define ACS 68             // f32 LDS acc row stride (272B: conflict-free flush + frag reads)

typedef __attribute__((ext_vector_type(8))) short bf16x8;
typedef __attribute__((ext_vector_type(4))) float f32x4;

__device__ __forceinline__ float fast_tanh(float x) {
    float e = __builtin_amdgcn_exp2f(x * 2.885390082f);
    return 1.f - 2.f * __builtin_amdgcn_rcpf(e + 1.f);
}

__device__ __forceinline__ void atomAddF(float* p, float v) {
#if defined(__AMDGCN__)
    unsafeAtomicAdd(p, v);
#else
    atomicAdd(p, v);
#endif
}

__device__ __forceinline__ short f2b(float f) {
    union { __hip_bfloat16 h; short s; } u;
    u.h = __float2bfloat16(f);
    return u.s;
}
__device__ __forceinline__ float b2f(unsigned short u) {
    return __uint_as_float(((unsigned int)u) << 16);
}
__device__ __forceinline__ unsigned int pack2(float lo, float hi) {
    return (unsigned int)(unsigned short)f2b(lo) | (((unsigned int)(unsigned short)f2b(hi)) << 16);
}

__device__ __forceinline__ int xcd_swz(int bid, int nwg) {
    int xcd = bid & 7, idx = bid >> 3;
    int q = nwg >> 3, r = nwg & 7;
    return (xcd < r ? xcd * (q + 1) : r * (q + 1) + (xcd - r) * q) + idx;
}

// KMEGA0: histogram (+rank record) + encoders in one launch.
__global__ void kmega0(const int* __restrict__ dst, int* __restrict__ cnt, int* __restrict__ rank,
                       const float* __restrict__ x,
                       const float* __restrict__ WencP1, const float* __restrict__ bencP1,
                       const float* __restrict__ WencP2, const float* __restrict__ bencP2,
                       __hip_bfloat16* __restrict__ h1b, __hip_bfloat16* __restrict__ h2b,
                       __hip_bfloat16* __restrict__ xb) {
    if (blockIdx.x < HIST_BLOCKS) {
        int e = blockIdx.x * 256 + threadIdx.x;
        rank[e] = atomicAdd(&cnt[dst[e]], 1);
    } else {
        int tid = (blockIdx.x - HIST_BLOCKS) * 256 + threadIdx.x;
        int n = tid >> 5;
        int j = tid & 31;
        if (n >= NN) return;
        const float* xr = x + (size_t)n * IN_DIM;
        float a1 = bencP1[j], a2 = bencP2[j];
        #pragma unroll
        for (int k = 0; k < 32; k++) {
            float q = xr[k];
            a1 = fmaf(q, WencP1[k * 32 + j], a1);
            a2 = fmaf(q, WencP2[k * 32 + j], a2);
        }
        union { __hip_bfloat16 h; short s; } u1, u2, u3, u4;
        u1.s = f2b(a1); u2.s = f2b(a2);
        h1b[(size_t)n * 32 + j] = u1.h;
        h2b[(size_t)n * 32 + j] = u2.h;
        u3.s = f2b(xr[j]); u4.s = f2b(xr[32 + j]);
        xb[(size_t)n * 64 + j] = u3.h;
        xb[(size_t)n * 64 + 32 + j] = u4.h;
    }
}

// 3-phase coalesced exclusive scan of cnt[NN] -> rowptr[NN+1]; kscanC also fills dstp.
__global__ void kscanA(const int* __restrict__ cnt, int* __restrict__ blocksum) {
    __shared__ int s[256];
    int t = threadIdx.x;
    int i = blockIdx.x * 256 + t;
    s[t] = (i < NN) ? cnt[i] : 0;
    __syncthreads();
    #pragma unroll
    for (int off = 128; off > 0; off >>= 1) {
        if (t < off) s[t] += s[t + off];
        __syncthreads();
    }
    if (t == 0) blocksum[blockIdx.x] = s[0];
}

__global__ void kscanB(const int* __restrict__ blocksum, int* __restrict__ blockoff) {
    __shared__ int part[256];
    int t = threadIdx.x;
    int v = (t < SCAN_NB) ? blocksum[t] : 0;
    part[t] = v;
    __syncthreads();
    for (int off = 1; off < 256; off <<= 1) {
        int u = (t >= off) ? part[t - off] : 0;
        __syncthreads();
        part[t] += u;
        __syncthreads();
    }
    if (t < SCAN_NB) blockoff[t] = part[t] - v;  // exclusive
}

__global__ void kscanC(const int* __restrict__ cnt, const int* __restrict__ blockoff,
                       int* __restrict__ rowptr, int* __restrict__ dstp) {
    __shared__ int part[256];
    int t = threadIdx.x;
    int i = blockIdx.x * 256 + t;
    int v = (i < NN) ? cnt[i] : 0;
    part[t] = v;
    __syncthreads();
    for (int off = 1; off < 256; off <<= 1) {
        int u = (t >= off) ? part[t - off] : 0;
        __syncthreads();
        part[t] += u;
        __syncthreads();
    }
    if (i < NN) {
        int incl = blockoff[blockIdx.x] + part[t];
        int lo = incl - v;
        rowptr[i] = lo;
        if (i == NN - 1) rowptr[NN] = incl;
        for (int p = lo; p < incl; p++) dstp[p] = i;   // fused dstp fill
    }
}

// KSCATTER: atomic-free placement using precomputed rank.
__global__ void kscatter(const int* __restrict__ src, const int* __restrict__ dst,
                         const int* __restrict__ rowptr, const int* __restrict__ rank,
                         int* __restrict__ srcp) {
    int e = blockIdx.x * 256 + threadIdx.x;
    if (e >= EE) return;
    int d = dst[e];
    srcp[rowptr[d] + rank[e]] = src[e];
}

// KMEGA2 (fused kxagg3 + k3ab): one wave per 16-node tile.
//   Phase A: walk the tile's contiguous sorted-edge range, gather xb rows,
//            carry-merge dst-runs into wave-private LDS f32 acc [16][ACS].
//   Phase B: dagg (MFMA) + hKagg (MFMA, bf16 LDS) + 3-layer node MLP -> EnodeT.
// No atomics, no xagg HBM buffer; degree from rowptr diff.
__global__ void __launch_bounds__(256) kmega2(
    const int* __restrict__ rowptr,
    const int* __restrict__ srcp, const int* __restrict__ dstp,
    const __hip_bfloat16* __restrict__ xb,
    const float* __restrict__ WencK, const float* __restrict__ bencK,
    const float* __restrict__ WD, const float* __restrict__ bD,
    const float* __restrict__ WK1, const float* __restrict__ bK1,
    const float* __restrict__ WK2, const float* __restrict__ bK2,
    const float* __restrict__ WK3, const float* __restrict__ bK3,
    float* __restrict__ dagg, __hip_bfloat16* __restrict__ EnodeT)
{
    __shared__ float accs[4][16 * ACS];
    __shared__ unsigned short xpose[4][16 * XPS];
    const int wid  = threadIdx.x >> 6;
    const int lane = threadIdx.x & 63;
    const int g = lane >> 4;
    const int r = lane & 15;
    float* accL = accs[wid];
    unsigned short* xp = xpose[wid];
    const unsigned short* xu = reinterpret_cast<const unsigned short*>(xb);

    // ---- weight fragments ----
    bf16x8 bwd[2][2];
    #pragma unroll
    for (int c = 0; c < 2; c++)
        #pragma unroll
        for (int nd = 0; nd < 2; nd++)
            #pragma unroll
            for (int i = 0; i < 8; i++)
                bwd[c][nd][i] = f2b(WD[(c * 32 + g * 8 + i) * 64 + 32 + nd * 16 + r]);
    bf16x8 bwk[2];
    #pragma unroll
    for (int nd = 0; nd < 2; nd++)
        #pragma unroll
        for (int i = 0; i < 8; i++)
            bwk[nd][i] = f2b(WencK[(g * 8 + i) * 32 + nd * 16 + r]);
    bf16x8 b1[4];
    #pragma unroll
    for (int nt = 0; nt < 4; nt++)
        #pragma unroll
        for (int i = 0; i < 8; i++)
            b1[nt][i] = f2b(WK1[(g * 8 + i) * 64 + nt * 16 + r]);
    bf16x8 b2[2][4], b3[2][4];
    #pragma unroll
    for (int c = 0; c < 2; c++)
        #pragma unroll
        for (int nt = 0; nt < 4; nt++)
            #pragma unroll
            for (int i = 0; i < 8; i++) {
                b2[c][nt][i] = f2b(WK2[(c * 32 + g * 8 + i) * 64 + nt * 16 + r]);
                b3[c][nt][i] = f2b(WK3[(c * 32 + g * 8 + i) * 64 + nt * 16 + r]);
            }
    float bdv[2], bkv[2];
    #pragma unroll
    for (int nd = 0; nd < 2; nd++) {
        bdv[nd] = bD[32 + nd * 16 + r];
        bkv[nd] = bencK[nd * 16 + r];
    }
    float bias1[4], bias2[4], bias3[4];
    #pragma unroll
    for (int nt = 0; nt < 4; nt++) {
        bias1[nt] = bK1[nt * 16 + r];
        bias2[nt] = bK2[nt * 16 + r];
        bias3[nt] = bK3[nt * 16 + r];
    }

    const int ntiles = NN / 16;            // 3125 exact
    const int wave = blockIdx.x * 4 + wid;
    const int nw = gridDim.x * 4;
    const f32x4 zero = {0.f, 0.f, 0.f, 0.f};

    for (int tile = wave; tile < ntiles; tile += nw) {
        const int bn = tile * 16;
        // ---- phase A: zero acc, walk edges, carry-merge into LDS ----
        #pragma unroll
        for (int i = 0; i < 16; i++) accL[i * ACS + lane] = 0.f;   // 2-way bank, free

        const int lo = rowptr[bn], hi = rowptr[bn + 16];
        int cd = -1;
        float carry = 0.f;
        for (int cb = lo; cb < hi; cb += 64) {
            int myp = cb + lane;
            bool valid = myp < hi;
            int sarr = valid ? srcp[myp] : 0;          // coalesced 256B
            int darr = valid ? dstp[myp] : 0;          // coalesced 256B
            int cnum = hi - cb; if (cnum > 64) cnum = 64;
            int s0 = __shfl(sarr, 0);
            float v = b2f(xu[(size_t)s0 * 64 + lane]);
            for (int t = 0; t < cnum; t++) {
                float cur = v;
                if (t + 1 < cnum) {
                    int sn = __shfl(sarr, t + 1);
                    v = b2f(xu[(size_t)sn * 64 + lane]);   // prefetch next row
                }
                int d = __shfl(darr, t);
                if (d != cd) {
                    if (cd >= 0) accL[(cd - bn) * ACS + lane] = carry;
                    cd = d; carry = 0.f;
                }
                carry += cur;
            }
        }
        if (cd >= 0) accL[(cd - bn) * ACS + lane] = carry;
        // wave-private LDS: same-wave DS ops are in-order, no barrier needed

        // ---- phase B: MFMA section (reads accL rows) ----
        bf16x8 ax0, ax1;
        {
            const float* ar = accL + r * ACS + g * 8;
            #pragma unroll
            for (int i = 0; i < 8; i++) ax0[i] = f2b(ar[i]);
            #pragma unroll
            for (int i = 0; i < 8; i++) ax1[i] = f2b(ar[32 + i]);
        }
        float cq[4];
        #pragma unroll
        for (int q = 0; q < 4; q++) {
            int n = bn + g * 4 + q;
            cq[q] = (float)(rowptr[n + 1] - rowptr[n]);
        }

        f32x4 accd[2];
        #pragma unroll
        for (int nd = 0; nd < 2; nd++) {
            accd[nd] = __builtin_amdgcn_mfma_f32_16x16x32_bf16(ax0, bwd[0][nd], zero, 0, 0, 0);
            accd[nd] = __builtin_amdgcn_mfma_f32_16x16x32_bf16(ax1, bwd[1][nd], accd[nd], 0, 0, 0);
        }
        #pragma unroll
        for (int nd = 0; nd < 2; nd++)
            #pragma unroll
            for (int q = 0; q < 4; q++)
                dagg[((size_t)bn + g * 4 + q) * 32 + nd * 16 + r] =
                    accd[nd][q] + cq[q] * bdv[nd];

        f32x4 acch[2];
        #pragma unroll
        for (int nd = 0; nd < 2; nd++)
            acch[nd] = __builtin_amdgcn_mfma_f32_16x16x32_bf16(ax1, bwk[nd], zero, 0, 0, 0);
        #pragma unroll
        for (int nd = 0; nd < 2; nd++)
            #pragma unroll
            for (int q = 0; q < 4; q++)
                xp[(g * 4 + q) * XPS + nd * 16 + r] = (unsigned short)f2b(acch[nd][q] + cq[q] * bkv[nd]);

        bf16x8 af = *reinterpret_cast<const bf16x8*>(xp + r * XPS + g * 8);
        f32x4 acc[4];
        #pragma unroll
        for (int nt = 0; nt < 4; nt++)
            acc[nt] = __builtin_amdgcn_mfma_f32_16x16x32_bf16(af, b1[nt], zero, 0, 0, 0);
        #pragma unroll
        for (int nt = 0; nt < 4; nt++)
            #pragma unroll
            for (int q = 0; q < 4; q++)
                xp[(g * 4 + q) * XPS + nt * 16 + r] = (unsigned short)f2b(fast_tanh(acc[nt][q] + bias1[nt]));

        f32x4 acc2[4] = {zero, zero, zero, zero};
        #pragma unroll
        for (int c = 0; c < 2; c++) {
            bf16x8 a2 = *reinterpret_cast<const bf16x8*>(xp + r * XPS + c * 32 + g * 8);
            #pragma unroll
            for (int nt = 0; nt < 4; nt++)
                acc2[nt] = __builtin_amdgcn_mfma_f32_16x16x32_bf16(a2, b2[c][nt], acc2[nt], 0, 0, 0);
        }
        #pragma unroll
        for (int nt = 0; nt < 4; nt++)
            #pragma unroll
            for (int q = 0; q < 4; q++)
                xp[(g * 4 + q) * XPS + nt * 16 + r] = (unsigned short)f2b(fmaxf(acc2[nt][q] + bias2[nt], 0.f));

        f32x4 acc3[4] = {zero, zero, zero, zero};
        #pragma unroll
        for (int c = 0; c < 2; c++) {
            bf16x8 a3 = *reinterpret_cast<const bf16x8*>(xp + r * XPS + c * 32 + g * 8);
            #pragma unroll
            for (int nt = 0; nt < 4; nt++)
                acc3[nt] = __builtin_amdgcn_mfma_f32_16x16x32_bf16(a3, b3[c][nt], acc3[nt], 0, 0, 0);
        }
        #pragma unroll
        for (int q = 0; q < 4; q++) {
            uint2 v;
            v.x = pack2(acc3[0][q] + bias3[0], acc3[1][q] + bias3[1]);
            v.y = pack2(acc3[2][q] + bias3[2], acc3[3][q] + bias3[3]);
            *reinterpret_cast<uint2*>(reinterpret_cast<unsigned short*>(EnodeT)
                + ((size_t)bn + g * 4 + q) * 64 + r * 4) = v;
        }
    }
}

// K4 v10: permuted EnodeT gather (1x8B per q) + instruction-coalesced Enew flush.
__global__ void __launch_bounds__(256) k4_mfma(
    const int* __restrict__ srcp, const int* __restrict__ dstp,
    const __hip_bfloat16* __restrict__ h1b, const __hip_bfloat16* __restrict__ h2b,
    const __hip_bfloat16* __restrict__ EnodeT, float* __restrict__ Enew,
    const float* __restrict__ WU1, const float* __restrict__ bU1,
    const float* __restrict__ WU2, const float* __restrict__ bU2,
    const float* __restrict__ WU3, const float* __restrict__ bU3)
{
    __shared__ unsigned short xpose[4][16 * XPS];
    const int wid  = threadIdx.x >> 6;
    const int lane = threadIdx.x & 63;
    const int g = lane >> 4;
    const int r = lane & 15;
    unsigned short* xp = xpose[wid];

    bf16x8 b1[4];
    #pragma unroll
    for (int nt = 0; nt < 4; nt++) {
        #pragma unroll
        for (int i = 0; i < 8; i++)
            b1[nt][i] = f2b(WU1[(g * 8 + i) * 64 + nt * 16 + r]);
    }
    bf16x8 b2[2][4], b3[2][4];
    #pragma unroll
    for (int c = 0; c < 2; c++) {
        #pragma unroll
        for (int nt = 0; nt < 4; nt++) {
            #pragma unroll
            for (int i = 0; i < 8; i++) {
                b2[c][nt][i] = f2b(WU2[(c * 32 + g * 8 + i) * 64 + nt * 16 + r]);
                b3[c][nt][i] = f2b(WU3[(c * 32 + g * 8 + i) * 64 + nt * 16 + r]);
            }
        }
    }
    float bias1[4], bias2[4], bias3[4];
    #pragma unroll
    for (int nt = 0; nt < 4; nt++) {
        bias1[nt] = bU1[nt * 16 + r];
        bias2[nt] = bU2[nt * 16 + r];
        bias3[nt] = bU3[nt * 16 + r];
    }

    const int sbid = xcd_swz(blockIdx.x, K4_NWG);
    const int wave = sbid * 4 + wid;
    const int base = wave * K4_EPW;
    const f32x4 zero = {0.f, 0.f, 0.f, 0.f};
    const unsigned short* enT = reinterpret_cast<const unsigned short*>(EnodeT);

    int   cd[4] = {-1, -1, -1, -1};
    float cv0[4] = {0, 0, 0, 0}, cv1[4] = {0, 0, 0, 0},
          cv2[4] = {0, 0, 0, 0}, cv3[4] = {0, 0, 0, 0};

    int sp = srcp[base + r * K4_C];
    int dp = dstp[base + r * K4_C];
    uint4 v1 = *reinterpret_cast<const uint4*>(h1b + (size_t)sp * 32 + g * 8);
    uint4 v2 = *reinterpret_cast<const uint4*>(h2b + (size_t)dp * 32 + g * 8);

    for (int t = 0; t < K4_C; t++) {
        const int s_me = sp, d_me = dp;
        union { uint4 v; bf16x8 b; } ua1, ua2;
        ua1.v = v1; ua2.v = v2;
        if (t + 1 < K4_C) {
            sp = srcp[base + r * K4_C + t + 1];
            dp = dstp[base + r * K4_C + t + 1];
            v1 = *reinterpret_cast<const uint4*>(h1b + (size_t)sp * 32 + g * 8);
            v2 = *reinterpret_cast<const uint4*>(h2b + (size_t)dp * 32 + g * 8);
        }

        int dq[4];
        float en0[4], en1[4], en2[4], en3[4];
        #pragma unroll
        for (int q = 0; q < 4; q++) {
            const int er = g * 4 + q;
            const int ssv = __shfl(s_me, er);
            dq[q] = __shfl(d_me, er);
            uint2 ev = *reinterpret_cast<const uint2*>(enT + (size_t)ssv * 64 + r * 4);
            en0[q] = b2f((unsigned short)(ev.x & 0xffff));
            en1[q] = b2f((unsigned short)(ev.x >> 16));
            en2[q] = b2f((unsigned short)(ev.y & 0xffff));
            en3[q] = b2f((unsigned short)(ev.y >> 16));
        }

        __builtin_amdgcn_s_setprio(1);
        f32x4 acc[4];
        #pragma unroll
        for (int nt = 0; nt < 4; nt++) {
            acc[nt] = __builtin_amdgcn_mfma_f32_16x16x32_bf16(ua2.b, b1[nt], zero, 0, 0, 0);
            acc[nt] = __builtin_amdgcn_mfma_f32_16x16x32_bf16(ua1.b, b1[nt], acc[nt], 0, 0, 0);
        }

        #pragma unroll
        for (int nt = 0; nt < 4; nt++) {
            #pragma unroll
            for (int q = 0; q < 4; q++)
                xp[(g * 4 + q) * XPS + nt * 16 + r] = (unsigned short)f2b(fast_tanh(acc[nt][q] + bias1[nt]));
        }

        f32x4 acc2[4] = {zero, zero, zero, zero};
        #pragma unroll
        for (int c = 0; c < 2; c++) {
            bf16x8 af = *reinterpret_cast<const bf16x8*>(xp + r * XPS + c * 32 + g * 8);
            #pragma unroll
            for (int nt = 0; nt < 4; nt++)
                acc2[nt] = __builtin_amdgcn_mfma_f32_16x16x32_bf16(af, b2[c][nt], acc2[nt], 0, 0, 0);
        }
        #pragma unroll
        for (int nt = 0; nt < 4; nt++) {
            #pragma unroll
            for (int q = 0; q < 4; q++)
                xp[(g * 4 + q) * XPS + nt * 16 + r] = (unsigned short)f2b(fmaxf(acc2[nt][q] + bias2[nt], 0.f));
        }

        f32x4 acc3[4] = {zero, zero, zero, zero};
        #pragma unroll
        for (int c = 0; c < 2; c++) {
            bf16x8 af = *reinterpret_cast<const bf16x8*>(xp + r * XPS + c * 32 + g * 8);
            #pragma unroll
            for (int nt = 0; nt < 4; nt++)
                acc3[nt] = __builtin_amdgcn_mfma_f32_16x16x32_bf16(af, b3[c][nt], acc3[nt], 0, 0, 0);
        }
        __builtin_amdgcn_s_setprio(0);

        #pragma unroll
        for (int q = 0; q < 4; q++) {
            float w0 = (acc3[0][q] + bias3[0]) * en0[q];
            float w1 = (acc3[1][q] + bias3[1]) * en1[q];
            float w2 = (acc3[2][q] + bias3[2]) * en2[q];
            float w3 = (acc3[3][q] + bias3[3]) * en3[q];
            if (dq[q] == cd[q]) {
                cv0[q] += w0; cv1[q] += w1; cv2[q] += w2; cv3[q] += w3;
            } else {
                if (cd[q] >= 0) {
                    float* ew = Enew + (size_t)cd[q] * 64 + r;   // instruction-coalesced
                    atomAddF(ew,      cv0[q]);
                    atomAddF(ew + 16, cv1[q]);
                    atomAddF(ew + 32, cv2[q]);
                    atomAddF(ew + 48, cv3[q]);
                }
                cd[q] = dq[q];
                cv0[q] = w0; cv1[q] = w1; cv2[q] = w2; cv3[q] = w3;
            }
        }
    }
    #pragma unroll
    for (int q = 0; q < 4; q++) {
        if (cd[q] >= 0) {
            float* ew = Enew + (size_t)cd[q] * 64 + r;
            atomAddF(ew,      cv0[q]);
            atomAddF(ew + 16, cv1[q]);
            atomAddF(ew + 32, cv2[q]);
            atomAddF(ew + 48, cv3[q]);
        }
    }
}

// K5: dH = E_new @ WH + bH ; out = [dH[:,32:], -dH[:,:32] - dagg]
__global__ void k5_out(const float* __restrict__ Enew, const float* __restrict__ dagg,
                       const float* __restrict__ WH, const float* __restrict__ bH,
                       float* __restrict__ out) {
    int tid = blockIdx.x * blockDim.x + threadIdx.x;
    int n = tid >> 6;
    int j = tid & 63;
    if (n >= NN) return;
    const float* er = Enew + (size_t)n * 64;
    int jj = (j < 32) ? (j + 32) : (j - 32);
    float acc = bH[jj];
    #pragma unroll
    for (int k = 0; k < 64; k++) acc = fmaf(er[k], WH[k * 64 + jj], acc);
    float val;
    if (j < 32) val = acc;
    else        val = -acc - dagg[(size_t)n * 32 + (j - 32)];
    out[tid] = val;
}

extern "C" void kernel_launch(void* const* d_in, const int* in_sizes, int n_in,
                              void* d_out, int out_size, void* d_ws, size_t ws_size,
                              hipStream_t stream) {
    const float* x      = (const float*)d_in[0];
    const int*   src    = (const int*)d_in[1];
    const int*   dst    = (const int*)d_in[2];
    const float* WencK  = (const float*)d_in[3];
    const float* bencK  = (const float*)d_in[4];
    const float* WencP1 = (const float*)d_in[5];
    const float* bencP1 = (const float*)d_in[6];
    const float* WencP2 = (const float*)d_in[7];
    const float* bencP2 = (const float*)d_in[8];
    const float* WK1    = (const float*)d_in[9];
    const float* bK1    = (const float*)d_in[10];
    const float* WK2    = (const float*)d_in[11];
    const float* bK2    = (const float*)d_in[12];
    const float* WK3    = (const float*)d_in[13];
    const float* bK3    = (const float*)d_in[14];
    const float* WU1    = (const float*)d_in[15];
    const float* bU1    = (const float*)d_in[16];
    const float* WU2    = (const float*)d_in[17];
    const float* bU2    = (const float*)d_in[18];
    const float* WU3    = (const float*)d_in[19];
    const float* bU3    = (const float*)d_in[20];
    const float* WH     = (const float*)d_in[21];
    const float* bH     = (const float*)d_in[22];
    const float* WD     = (const float*)d_in[23];
    const float* bD     = (const float*)d_in[24];
    float* out = (float*)d_out;

    // ---- workspace layout (~48.5 MB) ----
    float* Enew = (float*)d_ws;                                  // NN*64 f32
    float* dagg = Enew + (size_t)NN * 64;                        // NN*32 f32
    __hip_bfloat16* h1b    = (__hip_bfloat16*)(dagg + (size_t)NN * 32);  // NN*32 bf16
    __hip_bfloat16* h2b    = h1b + (size_t)NN * 32;              // NN*32 bf16
    __hip_bfloat16* EnodeT = h2b + (size_t)NN * 32;              // NN*64 bf16 (permuted)
    __hip_bfloat16* xb     = EnodeT + (size_t)NN * 64;           // NN*64 bf16
    int*  cnt      = (int*)(xb + (size_t)NN * 64);               // NN
    int*  rowptr   = cnt + NN;                                   // NN+2 (pad)
    int*  blocksum = rowptr + NN + 2;                            // 256
    int*  blockoff = blocksum + 256;                             // 256
    int*  rank     = blockoff + 256;                             // EE
    int*  srcp     = rank + EE;                                  // EE
    int*  dstp     = srcp + EE;                                  // EE
    size_t need = (size_t)NN * 96 * 4 + (size_t)NN * 192 * 2
                + ((size_t)NN * 2 + 2 + 512) * 4 + (size_t)EE * 12;
    if (ws_size < need) return;

    hipMemsetAsync(cnt, 0, (size_t)NN * sizeof(int), stream);
    hipMemsetAsync(Enew, 0, (size_t)NN * 64 * sizeof(float), stream);

    kmega0<<<HIST_BLOCKS + ENC_BLOCKS, 256, 0, stream>>>(
        dst, cnt, rank, x, WencP1, bencP1, WencP2, bencP2, h1b, h2b, xb);
    kscanA<<<SCAN_NB, 256, 0, stream>>>(cnt, blocksum);
    kscanB<<<1, 256, 0, stream>>>(blocksum, blockoff);
    kscanC<<<SCAN_NB, 256, 0, stream>>>(cnt, blockoff, rowptr, dstp);
    kscatter<<<HIST_BLOCKS, 256, 0, stream>>>(src, dst, rowptr, rank, srcp);
    kmega2<<<782, 256, 0, stream>>>(rowptr, srcp, dstp, xb, WencK, bencK, WD, bD,
                                    WK1, bK1, WK2, bK2, WK3, bK3, dagg, EnodeT);
    k4_mfma<<<K4_NWG, 256, 0, stream>>>(srcp, dstp, h1b, h2b, EnodeT, Enew,
                                        WU1, bU1, WU2, bU2, WU3, bU3);
    k5_out<<<(NN * 64 + 255) / 256, 256, 0, stream>>>(Enew, dagg, WH, bH, out);
}

// Round 15
// 253.671 us; speedup vs baseline: 1.6782x; 1.6782x over previous
//
#include <hip/hip_runtime.h>
#include <hip/hip_bf16.h>

#define NN 50000
#define EE 800000
#define IN_DIM 64
#define DS_DIM 32
#define HOUT_DIM 64

#define K4_WAVES 10000
#define K4_EPW   80
#define K4_C     5
#define K4_NWG   (K4_WAVES / 4)   // 2500

#define XA_EPW 32
#define XA_NWG 6250               // 25000 waves

#define HIST_BLOCKS 3125   // EE/256
#define ENC_BLOCKS  6250   // NN*32/256

#define SCAN_NB 196        // ceil(NN/256)

#define XPS 72             // LDS row stride in bf16 (144B = 9*16B)

typedef __attribute__((ext_vector_type(8))) short bf16x8;
typedef __attribute__((ext_vector_type(4))) float f32x4;

__device__ __forceinline__ float fast_tanh(float x) {
    float e = __builtin_amdgcn_exp2f(x * 2.885390082f);
    return 1.f - 2.f * __builtin_amdgcn_rcpf(e + 1.f);
}

__device__ __forceinline__ void atomAddF(float* p, float v) {
#if defined(__AMDGCN__)
    unsafeAtomicAdd(p, v);
#else
    atomicAdd(p, v);
#endif
}

__device__ __forceinline__ short f2b(float f) {
    union { __hip_bfloat16 h; short s; } u;
    u.h = __float2bfloat16(f);
    return u.s;
}
__device__ __forceinline__ float b2f(unsigned short u) {
    return __uint_as_float(((unsigned int)u) << 16);
}
__device__ __forceinline__ unsigned int pack2(float lo, float hi) {
    return (unsigned int)(unsigned short)f2b(lo) | (((unsigned int)(unsigned short)f2b(hi)) << 16);
}

__device__ __forceinline__ int xcd_swz(int bid, int nwg) {
    int xcd = bid & 7, idx = bid >> 3;
    int q = nwg >> 3, r = nwg & 7;
    return (xcd < r ? xcd * (q + 1) : r * (q + 1) + (xcd - r) * q) + idx;
}

// KMEGA0: histogram (+rank record) + encoders in one launch.
__global__ void kmega0(const int* __restrict__ dst, int* __restrict__ cnt, int* __restrict__ rank,
                       const float* __restrict__ x,
                       const float* __restrict__ WencP1, const float* __restrict__ bencP1,
                       const float* __restrict__ WencP2, const float* __restrict__ bencP2,
                       __hip_bfloat16* __restrict__ h1b, __hip_bfloat16* __restrict__ h2b,
                       __hip_bfloat16* __restrict__ xb) {
    if (blockIdx.x < HIST_BLOCKS) {
        int e = blockIdx.x * 256 + threadIdx.x;
        rank[e] = atomicAdd(&cnt[dst[e]], 1);
    } else {
        int tid = (blockIdx.x - HIST_BLOCKS) * 256 + threadIdx.x;
        int n = tid >> 5;
        int j = tid & 31;
        if (n >= NN) return;
        const float* xr = x + (size_t)n * IN_DIM;
        float a1 = bencP1[j], a2 = bencP2[j];
        #pragma unroll
        for (int k = 0; k < 32; k++) {
            float q = xr[k];
            a1 = fmaf(q, WencP1[k * 32 + j], a1);
            a2 = fmaf(q, WencP2[k * 32 + j], a2);
        }
        union { __hip_bfloat16 h; short s; } u1, u2, u3, u4;
        u1.s = f2b(a1); u2.s = f2b(a2);
        h1b[(size_t)n * 32 + j] = u1.h;
        h2b[(size_t)n * 32 + j] = u2.h;
        u3.s = f2b(xr[j]); u4.s = f2b(xr[32 + j]);
        xb[(size_t)n * 64 + j] = u3.h;
        xb[(size_t)n * 64 + 32 + j] = u4.h;
    }
}

// 3-phase coalesced exclusive scan of cnt[NN] -> rowptr[NN+1]; kscanC also fills dstp.
__global__ void kscanA(const int* __restrict__ cnt, int* __restrict__ blocksum) {
    __shared__ int s[256];
    int t = threadIdx.x;
    int i = blockIdx.x * 256 + t;
    s[t] = (i < NN) ? cnt[i] : 0;
    __syncthreads();
    #pragma unroll
    for (int off = 128; off > 0; off >>= 1) {
        if (t < off) s[t] += s[t + off];
        __syncthreads();
    }
    if (t == 0) blocksum[blockIdx.x] = s[0];
}

__global__ void kscanB(const int* __restrict__ blocksum, int* __restrict__ blockoff) {
    __shared__ int part[256];
    int t = threadIdx.x;
    int v = (t < SCAN_NB) ? blocksum[t] : 0;
    part[t] = v;
    __syncthreads();
    for (int off = 1; off < 256; off <<= 1) {
        int u = (t >= off) ? part[t - off] : 0;
        __syncthreads();
        part[t] += u;
        __syncthreads();
    }
    if (t < SCAN_NB) blockoff[t] = part[t] - v;  // exclusive
}

__global__ void kscanC(const int* __restrict__ cnt, const int* __restrict__ blockoff,
                       int* __restrict__ rowptr, int* __restrict__ dstp) {
    __shared__ int part[256];
    int t = threadIdx.x;
    int i = blockIdx.x * 256 + t;
    int v = (i < NN) ? cnt[i] : 0;
    part[t] = v;
    __syncthreads();
    for (int off = 1; off < 256; off <<= 1) {
        int u = (t >= off) ? part[t - off] : 0;
        __syncthreads();
        part[t] += u;
        __syncthreads();
    }
    if (i < NN) {
        int incl = blockoff[blockIdx.x] + part[t];
        int lo = incl - v;
        rowptr[i] = lo;
        if (i == NN - 1) rowptr[NN] = incl;
        for (int p = lo; p < incl; p++) dstp[p] = i;   // fused dstp fill
    }
}

// KSCATTER: atomic-free placement using precomputed rank.
__global__ void kscatter(const int* __restrict__ src, const int* __restrict__ dst,
                         const int* __restrict__ rowptr, const int* __restrict__ rank,
                         int* __restrict__ srcp) {
    int e = blockIdx.x * 256 + threadIdx.x;
    if (e >= EE) return;
    int d = dst[e];
    srcp[rowptr[d] + rank[e]] = src[e];
}

// KXAGG3: edge-chunk carry-merged segment-sum of bf16 x rows into xagg (f32).
// 32-edge chunks (25000 waves) + 4-deep gather pipeline.
__global__ void __launch_bounds__(256) kxagg3(const int* __restrict__ srcp,
                                              const int* __restrict__ dstp,
                                              const __hip_bfloat16* __restrict__ xb,
                                              float* __restrict__ xagg) {
    int sbid = xcd_swz(blockIdx.x, XA_NWG);
    int w = sbid * 4 + (threadIdx.x >> 6);
    int lane = threadIdx.x & 63;
    int base = w * XA_EPW;
    const unsigned short* xu = reinterpret_cast<const unsigned short*>(xb);

    int sarr = srcp[base + (lane & 31)];   // coalesced 128B, in-bounds for last wave
    int darr = dstp[base + (lane & 31)];

    float v0 = b2f(xu[(size_t)__shfl(sarr, 0) * 64 + lane]);
    float v1 = b2f(xu[(size_t)__shfl(sarr, 1) * 64 + lane]);
    float v2 = b2f(xu[(size_t)__shfl(sarr, 2) * 64 + lane]);
    float v3 = b2f(xu[(size_t)__shfl(sarr, 3) * 64 + lane]);
    int cd = __shfl(darr, 0);
    float carry = 0.f;

#define XA_STEP(vv, T)                                                        \
    {                                                                         \
        float cur = vv;                                                       \
        if ((T) + 4 < XA_EPW)                                                 \
            vv = b2f(xu[(size_t)__shfl(sarr, (T) + 4) * 64 + lane]);          \
        int d = __shfl(darr, (T));                                            \
        if (d != cd) {                                                        \
            atomAddF(&xagg[(size_t)cd * 64 + lane], carry);                   \
            cd = d; carry = 0.f;                                              \
        }                                                                     \
        carry += cur;                                                         \
    }

    for (int tb = 0; tb < XA_EPW; tb += 4) {
        XA_STEP(v0, tb);
        XA_STEP(v1, tb + 1);
        XA_STEP(v2, tb + 2);
        XA_STEP(v3, tb + 3);
    }
#undef XA_STEP
    atomAddF(&xagg[(size_t)cd * 64 + lane], carry);
}

// K3AB: dagg (MFMA) + hKagg (MFMA, bf16 LDS) + node MLP -> EnodeT[node][r*4+nt]
// (permuted layout on the GATHER side only).
__global__ void __launch_bounds__(256) k3ab(
    const float* __restrict__ xagg, const int* __restrict__ cnt,
    const float* __restrict__ WencK, const float* __restrict__ bencK,
    const float* __restrict__ WD, const float* __restrict__ bD,
    const float* __restrict__ WK1, const float* __restrict__ bK1,
    const float* __restrict__ WK2, const float* __restrict__ bK2,
    const float* __restrict__ WK3, const float* __restrict__ bK3,
    float* __restrict__ dagg, __hip_bfloat16* __restrict__ EnodeT)
{
    __shared__ unsigned short xpose[4][16 * XPS];
    const int wid  = threadIdx.x >> 6;
    const int lane = threadIdx.x & 63;
    const int g = lane >> 4;
    const int r = lane & 15;
    unsigned short* xp = xpose[wid];

    bf16x8 bwd[2][2];
    #pragma unroll
    for (int c = 0; c < 2; c++)
        #pragma unroll
        for (int nd = 0; nd < 2; nd++)
            #pragma unroll
            for (int i = 0; i < 8; i++)
                bwd[c][nd][i] = f2b(WD[(c * 32 + g * 8 + i) * 64 + 32 + nd * 16 + r]);
    bf16x8 bwk[2];
    #pragma unroll
    for (int nd = 0; nd < 2; nd++)
        #pragma unroll
        for (int i = 0; i < 8; i++)
            bwk[nd][i] = f2b(WencK[(g * 8 + i) * 32 + nd * 16 + r]);
    bf16x8 b1[4];
    #pragma unroll
    for (int nt = 0; nt < 4; nt++)
        #pragma unroll
        for (int i = 0; i < 8; i++)
            b1[nt][i] = f2b(WK1[(g * 8 + i) * 64 + nt * 16 + r]);
    bf16x8 b2[2][4], b3[2][4];
    #pragma unroll
    for (int c = 0; c < 2; c++)
        #pragma unroll
        for (int nt = 0; nt < 4; nt++)
            #pragma unroll
            for (int i = 0; i < 8; i++) {
                b2[c][nt][i] = f2b(WK2[(c * 32 + g * 8 + i) * 64 + nt * 16 + r]);
                b3[c][nt][i] = f2b(WK3[(c * 32 + g * 8 + i) * 64 + nt * 16 + r]);
            }
    float bdv[2], bkv[2];
    #pragma unroll
    for (int nd = 0; nd < 2; nd++) {
        bdv[nd] = bD[32 + nd * 16 + r];
        bkv[nd] = bencK[nd * 16 + r];
    }
    float bias1[4], bias2[4], bias3[4];
    #pragma unroll
    for (int nt = 0; nt < 4; nt++) {
        bias1[nt] = bK1[nt * 16 + r];
        bias2[nt] = bK2[nt * 16 + r];
        bias3[nt] = bK3[nt * 16 + r];
    }

    const int ntiles = NN / 16;            // 3125 exact
    const int wave = blockIdx.x * 4 + wid;
    const int nw = gridDim.x * 4;
    const f32x4 zero = {0.f, 0.f, 0.f, 0.f};

    for (int tile = wave; tile < ntiles; tile += nw) {
        bf16x8 ax0, ax1;
        {
            const float* xr = xagg + ((size_t)tile * 16 + r) * 64 + g * 8;
            float4 p0 = *reinterpret_cast<const float4*>(xr);
            float4 p1 = *reinterpret_cast<const float4*>(xr + 4);
            float4 p2 = *reinterpret_cast<const float4*>(xr + 32);
            float4 p3 = *reinterpret_cast<const float4*>(xr + 36);
            ax0[0] = f2b(p0.x); ax0[1] = f2b(p0.y); ax0[2] = f2b(p0.z); ax0[3] = f2b(p0.w);
            ax0[4] = f2b(p1.x); ax0[5] = f2b(p1.y); ax0[6] = f2b(p1.z); ax0[7] = f2b(p1.w);
            ax1[0] = f2b(p2.x); ax1[1] = f2b(p2.y); ax1[2] = f2b(p2.z); ax1[3] = f2b(p2.w);
            ax1[4] = f2b(p3.x); ax1[5] = f2b(p3.y); ax1[6] = f2b(p3.z); ax1[7] = f2b(p3.w);
        }
        float cq[4];
        #pragma unroll
        for (int q = 0; q < 4; q++) cq[q] = (float)cnt[tile * 16 + g * 4 + q];

        f32x4 accd[2];
        #pragma unroll
        for (int nd = 0; nd < 2; nd++) {
            accd[nd] = __builtin_amdgcn_mfma_f32_16x16x32_bf16(ax0, bwd[0][nd], zero, 0, 0, 0);
            accd[nd] = __builtin_amdgcn_mfma_f32_16x16x32_bf16(ax1, bwd[1][nd], accd[nd], 0, 0, 0);
        }
        #pragma unroll
        for (int nd = 0; nd < 2; nd++)
            #pragma unroll
            for (int q = 0; q < 4; q++)
                dagg[((size_t)tile * 16 + g * 4 + q) * 32 + nd * 16 + r] =
                    accd[nd][q] + cq[q] * bdv[nd];

        f32x4 acch[2];
        #pragma unroll
        for (int nd = 0; nd < 2; nd++)
            acch[nd] = __builtin_amdgcn_mfma_f32_16x16x32_bf16(ax1, bwk[nd], zero, 0, 0, 0);
        #pragma unroll
        for (int nd = 0; nd < 2; nd++)
            #pragma unroll
            for (int q = 0; q < 4; q++)
                xp[(g * 4 + q) * XPS + nd * 16 + r] = (unsigned short)f2b(acch[nd][q] + cq[q] * bkv[nd]);

        bf16x8 af = *reinterpret_cast<const bf16x8*>(xp + r * XPS + g * 8);
        f32x4 acc[4];
        #pragma unroll
        for (int nt = 0; nt < 4; nt++)
            acc[nt] = __builtin_amdgcn_mfma_f32_16x16x32_bf16(af, b1[nt], zero, 0, 0, 0);
        #pragma unroll
        for (int nt = 0; nt < 4; nt++)
            #pragma unroll
            for (int q = 0; q < 4; q++)
                xp[(g * 4 + q) * XPS + nt * 16 + r] = (unsigned short)f2b(fast_tanh(acc[nt][q] + bias1[nt]));

        f32x4 acc2[4] = {zero, zero, zero, zero};
        #pragma unroll
        for (int c = 0; c < 2; c++) {
            bf16x8 a2 = *reinterpret_cast<const bf16x8*>(xp + r * XPS + c * 32 + g * 8);
            #pragma unroll
            for (int nt = 0; nt < 4; nt++)
                acc2[nt] = __builtin_amdgcn_mfma_f32_16x16x32_bf16(a2, b2[c][nt], acc2[nt], 0, 0, 0);
        }
        #pragma unroll
        for (int nt = 0; nt < 4; nt++)
            #pragma unroll
            for (int q = 0; q < 4; q++)
                xp[(g * 4 + q) * XPS + nt * 16 + r] = (unsigned short)f2b(fmaxf(acc2[nt][q] + bias2[nt], 0.f));

        f32x4 acc3[4] = {zero, zero, zero, zero};
        #pragma unroll
        for (int c = 0; c < 2; c++) {
            bf16x8 a3 = *reinterpret_cast<const bf16x8*>(xp + r * XPS + c * 32 + g * 8);
            #pragma unroll
            for (int nt = 0; nt < 4; nt++)
                acc3[nt] = __builtin_amdgcn_mfma_f32_16x16x32_bf16(a3, b3[c][nt], acc3[nt], 0, 0, 0);
        }
        // direct register stores into permuted EnodeT (8B per quadrant)
        #pragma unroll
        for (int q = 0; q < 4; q++) {
            uint2 v;
            v.x = pack2(acc3[0][q] + bias3[0], acc3[1][q] + bias3[1]);
            v.y = pack2(acc3[2][q] + bias3[2], acc3[3][q] + bias3[3]);
            *reinterpret_cast<uint2*>(reinterpret_cast<unsigned short*>(EnodeT)
                + ((size_t)tile * 16 + g * 4 + q) * 64 + r * 4) = v;
        }
    }
}

// K4 v10: permuted EnodeT gather (1x8B per q) + instruction-coalesced Enew flush.
__global__ void __launch_bounds__(256) k4_mfma(
    const int* __restrict__ srcp, const int* __restrict__ dstp,
    const __hip_bfloat16* __restrict__ h1b, const __hip_bfloat16* __restrict__ h2b,
    const __hip_bfloat16* __restrict__ EnodeT, float* __restrict__ Enew,
    const float* __restrict__ WU1, const float* __restrict__ bU1,
    const float* __restrict__ WU2, const float* __restrict__ bU2,
    const float* __restrict__ WU3, const float* __restrict__ bU3)
{
    __shared__ unsigned short xpose[4][16 * XPS];
    const int wid  = threadIdx.x >> 6;
    const int lane = threadIdx.x & 63;
    const int g = lane >> 4;
    const int r = lane & 15;
    unsigned short* xp = xpose[wid];

    bf16x8 b1[4];
    #pragma unroll
    for (int nt = 0; nt < 4; nt++) {
        #pragma unroll
        for (int i = 0; i < 8; i++)
            b1[nt][i] = f2b(WU1[(g * 8 + i) * 64 + nt * 16 + r]);
    }
    bf16x8 b2[2][4], b3[2][4];
    #pragma unroll
    for (int c = 0; c < 2; c++) {
        #pragma unroll
        for (int nt = 0; nt < 4; nt++) {
            #pragma unroll
            for (int i = 0; i < 8; i++) {
                b2[c][nt][i] = f2b(WU2[(c * 32 + g * 8 + i) * 64 + nt * 16 + r]);
                b3[c][nt][i] = f2b(WU3[(c * 32 + g * 8 + i) * 64 + nt * 16 + r]);
            }
        }
    }
    float bias1[4], bias2[4], bias3[4];
    #pragma unroll
    for (int nt = 0; nt < 4; nt++) {
        bias1[nt] = bU1[nt * 16 + r];
        bias2[nt] = bU2[nt * 16 + r];
        bias3[nt] = bU3[nt * 16 + r];
    }

    const int sbid = xcd_swz(blockIdx.x, K4_NWG);
    const int wave = sbid * 4 + wid;
    const int base = wave * K4_EPW;
    const f32x4 zero = {0.f, 0.f, 0.f, 0.f};
    const unsigned short* enT = reinterpret_cast<const unsigned short*>(EnodeT);

    int   cd[4] = {-1, -1, -1, -1};
    float cv0[4] = {0, 0, 0, 0}, cv1[4] = {0, 0, 0, 0},
          cv2[4] = {0, 0, 0, 0}, cv3[4] = {0, 0, 0, 0};

    int sp = srcp[base + r * K4_C];
    int dp = dstp[base + r * K4_C];
    uint4 v1 = *reinterpret_cast<const uint4*>(h1b + (size_t)sp * 32 + g * 8);
    uint4 v2 = *reinterpret_cast<const uint4*>(h2b + (size_t)dp * 32 + g * 8);

    for (int t = 0; t < K4_C; t++) {
        const int s_me = sp, d_me = dp;
        union { uint4 v; bf16x8 b; } ua1, ua2;
        ua1.v = v1; ua2.v = v2;
        if (t + 1 < K4_C) {
            sp = srcp[base + r * K4_C + t + 1];
            dp = dstp[base + r * K4_C + t + 1];
            v1 = *reinterpret_cast<const uint4*>(h1b + (size_t)sp * 32 + g * 8);
            v2 = *reinterpret_cast<const uint4*>(h2b + (size_t)dp * 32 + g * 8);
        }

        int dq[4];
        float en0[4], en1[4], en2[4], en3[4];
        #pragma unroll
        for (int q = 0; q < 4; q++) {
            const int er = g * 4 + q;
            const int ssv = __shfl(s_me, er);
            dq[q] = __shfl(d_me, er);
            uint2 ev = *reinterpret_cast<const uint2*>(enT + (size_t)ssv * 64 + r * 4);
            en0[q] = b2f((unsigned short)(ev.x & 0xffff));
            en1[q] = b2f((unsigned short)(ev.x >> 16));
            en2[q] = b2f((unsigned short)(ev.y & 0xffff));
            en3[q] = b2f((unsigned short)(ev.y >> 16));
        }

        __builtin_amdgcn_s_setprio(1);
        f32x4 acc[4];
        #pragma unroll
        for (int nt = 0; nt < 4; nt++) {
            acc[nt] = __builtin_amdgcn_mfma_f32_16x16x32_bf16(ua2.b, b1[nt], zero, 0, 0, 0);
            acc[nt] = __builtin_amdgcn_mfma_f32_16x16x32_bf16(ua1.b, b1[nt], acc[nt], 0, 0, 0);
        }

        #pragma unroll
        for (int nt = 0; nt < 4; nt++) {
            #pragma unroll
            for (int q = 0; q < 4; q++)
                xp[(g * 4 + q) * XPS + nt * 16 + r] = (unsigned short)f2b(fast_tanh(acc[nt][q] + bias1[nt]));
        }

        f32x4 acc2[4] = {zero, zero, zero, zero};
        #pragma unroll
        for (int c = 0; c < 2; c++) {
            bf16x8 af = *reinterpret_cast<const bf16x8*>(xp + r * XPS + c * 32 + g * 8);
            #pragma unroll
            for (int nt = 0; nt < 4; nt++)
                acc2[nt] = __builtin_amdgcn_mfma_f32_16x16x32_bf16(af, b2[c][nt], acc2[nt], 0, 0, 0);
        }
        #pragma unroll
        for (int nt = 0; nt < 4; nt++) {
            #pragma unroll
            for (int q = 0; q < 4; q++)
                xp[(g * 4 + q) * XPS + nt * 16 + r] = (unsigned short)f2b(fmaxf(acc2[nt][q] + bias2[nt], 0.f));
        }

        f32x4 acc3[4] = {zero, zero, zero, zero};
        #pragma unroll
        for (int c = 0; c < 2; c++) {
            bf16x8 af = *reinterpret_cast<const bf16x8*>(xp + r * XPS + c * 32 + g * 8);
            #pragma unroll
            for (int nt = 0; nt < 4; nt++)
                acc3[nt] = __builtin_amdgcn_mfma_f32_16x16x32_bf16(af, b3[c][nt], acc3[nt], 0, 0, 0);
        }
        __builtin_amdgcn_s_setprio(0);

        #pragma unroll
        for (int q = 0; q < 4; q++) {
            float w0 = (acc3[0][q] + bias3[0]) * en0[q];
            float w1 = (acc3[1][q] + bias3[1]) * en1[q];
            float w2 = (acc3[2][q] + bias3[2]) * en2[q];
            float w3 = (acc3[3][q] + bias3[3]) * en3[q];
            if (dq[q] == cd[q]) {
                cv0[q] += w0; cv1[q] += w1; cv2[q] += w2; cv3[q] += w3;
            } else {
                if (cd[q] >= 0) {
                    float* ew = Enew + (size_t)cd[q] * 64 + r;   // instruction-coalesced
                    atomAddF(ew,      cv0[q]);
                    atomAddF(ew + 16, cv1[q]);
                    atomAddF(ew + 32, cv2[q]);
                    atomAddF(ew + 48, cv3[q]);
                }
                cd[q] = dq[q];
                cv0[q] = w0; cv1[q] = w1; cv2[q] = w2; cv3[q] = w3;
            }
        }
    }
    #pragma unroll
    for (int q = 0; q < 4; q++) {
        if (cd[q] >= 0) {
            float* ew = Enew + (size_t)cd[q] * 64 + r;
            atomAddF(ew,      cv0[q]);
            atomAddF(ew + 16, cv1[q]);
            atomAddF(ew + 32, cv2[q]);
            atomAddF(ew + 48, cv3[q]);
        }
    }
}

// K5: dH = E_new @ WH + bH ; out = [dH[:,32:], -dH[:,:32] - dagg]
__global__ void k5_out(const float* __restrict__ Enew, const float* __restrict__ dagg,
                       const float* __restrict__ WH, const float* __restrict__ bH,
                       float* __restrict__ out) {
    int tid = blockIdx.x * blockDim.x + threadIdx.x;
    int n = tid >> 6;
    int j = tid & 63;
    if (n >= NN) return;
    const float* er = Enew + (size_t)n * 64;
    int jj = (j < 32) ? (j + 32) : (j - 32);
    float acc = bH[jj];
    #pragma unroll
    for (int k = 0; k < 64; k++) acc = fmaf(er[k], WH[k * 64 + jj], acc);
    float val;
    if (j < 32) val = acc;
    else        val = -acc - dagg[(size_t)n * 32 + (j - 32)];
    out[tid] = val;
}

extern "C" void kernel_launch(void* const* d_in, const int* in_sizes, int n_in,
                              void* d_out, int out_size, void* d_ws, size_t ws_size,
                              hipStream_t stream) {
    const float* x      = (const float*)d_in[0];
    const int*   src    = (const int*)d_in[1];
    const int*   dst    = (const int*)d_in[2];
    const float* WencK  = (const float*)d_in[3];
    const float* bencK  = (const float*)d_in[4];
    const float* WencP1 = (const float*)d_in[5];
    const float* bencP1 = (const float*)d_in[6];
    const float* WencP2 = (const float*)d_in[7];
    const float* bencP2 = (const float*)d_in[8];
    const float* WK1    = (const float*)d_in[9];
    const float* bK1    = (const float*)d_in[10];
    const float* WK2    = (const float*)d_in[11];
    const float* bK2    = (const float*)d_in[12];
    const float* WK3    = (const float*)d_in[13];
    const float* bK3    = (const float*)d_in[14];
    const float* WU1    = (const float*)d_in[15];
    const float* bU1    = (const float*)d_in[16];
    const float* WU2    = (const float*)d_in[17];
    const float* bU2    = (const float*)d_in[18];
    const float* WU3    = (const float*)d_in[19];
    const float* bU3    = (const float*)d_in[20];
    const float* WH     = (const float*)d_in[21];
    const float* bH     = (const float*)d_in[22];
    const float* WD     = (const float*)d_in[23];
    const float* bD     = (const float*)d_in[24];
    float* out = (float*)d_out;

    // ---- workspace layout (~61.2 MB, <= proven 64 MB) ----
    float* xagg = (float*)d_ws;                                  // NN*64 f32
    float* Enew = xagg + (size_t)NN * 64;                        // NN*64 f32
    float* dagg = Enew + (size_t)NN * 64;                        // NN*32 f32
    __hip_bfloat16* h1b    = (__hip_bfloat16*)(dagg + (size_t)NN * 32);  // NN*32 bf16
    __hip_bfloat16* h2b    = h1b + (size_t)NN * 32;              // NN*32 bf16
    __hip_bfloat16* EnodeT = h2b + (size_t)NN * 32;              // NN*64 bf16 (permuted)
    __hip_bfloat16* xb     = EnodeT + (size_t)NN * 64;           // NN*64 bf16
    int*  cnt      = (int*)(xb + (size_t)NN * 64);               // NN
    int*  rowptr   = cnt + NN;                                   // NN+2 (pad)
    int*  blocksum = rowptr + NN + 2;                            // 256
    int*  blockoff = blocksum + 256;                             // 256
    int*  rank     = blockoff + 256;                             // EE
    int*  srcp     = rank + EE;                                  // EE
    int*  dstp     = srcp + EE;                                  // EE
    size_t need = (size_t)NN * 160 * 4 + (size_t)NN * 192 * 2
                + ((size_t)NN * 2 + 2 + 512) * 4 + (size_t)EE * 12;
    if (ws_size < need) return;

    hipMemsetAsync(cnt, 0, (size_t)NN * sizeof(int), stream);
    hipMemsetAsync(xagg, 0, (size_t)NN * 128 * sizeof(float), stream);      // xagg + Enew

    kmega0<<<HIST_BLOCKS + ENC_BLOCKS, 256, 0, stream>>>(
        dst, cnt, rank, x, WencP1, bencP1, WencP2, bencP2, h1b, h2b, xb);
    kscanA<<<SCAN_NB, 256, 0, stream>>>(cnt, blocksum);
    kscanB<<<1, 256, 0, stream>>>(blocksum, blockoff);
    kscanC<<<SCAN_NB, 256, 0, stream>>>(cnt, blockoff, rowptr, dstp);
    kscatter<<<HIST_BLOCKS, 256, 0, stream>>>(src, dst, rowptr, rank, srcp);
    kxagg3<<<XA_NWG, 256, 0, stream>>>(srcp, dstp, xb, xagg);
    k3ab<<<782, 256, 0, stream>>>(xagg, cnt, WencK, bencK, WD, bD,
                                  WK1, bK1, WK2, bK2, WK3, bK3, dagg, EnodeT);
    k4_mfma<<<K4_NWG, 256, 0, stream>>>(srcp, dstp, h1b, h2b, EnodeT, Enew,
                                        WU1, bU1, WU2, bU2, WU3, bU3);
    k5_out<<<(NN * 64 + 255) / 256, 256, 0, stream>>>(Enew, dagg, WH, bH, out);
}